// Round 3
// baseline (419.334 us; speedup 1.0000x reference)
//
#include <hip/hip_runtime.h>
#include <hip/hip_bf16.h>

#define S_LEN 4096
#define DH 64
#define NBATCH 4

typedef __attribute__((ext_vector_type(8))) short bf16x8;   // 8 x bf16 (4 VGPRs)
typedef __attribute__((ext_vector_type(4))) short bf16x4;   // 4 x bf16
typedef __attribute__((ext_vector_type(4))) float f32x4;

static __device__ __forceinline__ short f2bf(float x) {
  __hip_bfloat16 h = __float2bfloat16(x);
  return *reinterpret_cast<short*>(&h);
}

#define MFMA(a, b, c) __builtin_amdgcn_mfma_f32_16x16x32_bf16((a), (b), (c), 0, 0, 0)

// ---- q fp32 -> bf16 ----
__global__ __launch_bounds__(256) void cvt_q_kernel(const float* __restrict__ q,
                                                    short* __restrict__ qb) {
  int i = (blockIdx.x * 256 + threadIdx.x) * 4;
  f32x4 x = *(const f32x4*)(q + i);
  bf16x4 o;
#pragma unroll
  for (int j = 0; j < 4; ++j) o[j] = f2bf(x[j]);
  *(bf16x4*)(qb + i) = o;
}

// ---- k,v fp32 -> pre-fragmented bf16 MFMA operand layout (unchanged) ----
__global__ __launch_bounds__(256) void cvt_frag_kernel(const float* __restrict__ k,
                                                       const float* __restrict__ v,
                                                       short* __restrict__ kfrag,
                                                       short* __restrict__ vfrag) {
  __shared__ short kt[32][80];
  __shared__ short vt[32][80];
  const int t = threadIdx.x;
  const int b = blockIdx.x >> 7;
  const int i = blockIdx.x & 127;
  const size_t src0 = ((size_t)b * S_LEN + i * 32) * DH;
  {
    const int row = t >> 3, c0 = (t & 7) * 8;
    const f32x4 xk0 = *(const f32x4*)(k + src0 + row * DH + c0);
    const f32x4 xk1 = *(const f32x4*)(k + src0 + row * DH + c0 + 4);
    const f32x4 xv0 = *(const f32x4*)(v + src0 + row * DH + c0);
    const f32x4 xv1 = *(const f32x4*)(v + src0 + row * DH + c0 + 4);
#pragma unroll
    for (int j = 0; j < 4; ++j) {
      kt[row][c0 + j] = f2bf(xk0[j]);  kt[row][c0 + 4 + j] = f2bf(xk1[j]);
      vt[row][c0 + j] = f2bf(xv0[j]);  vt[row][c0 + 4 + j] = f2bf(xv1[j]);
    }
  }
  __syncthreads();
  const int c = t >> 6, l = t & 63;
  const size_t dst = (((size_t)(b * 128 + i) * 4 + c) * 64 + l) * 8;
  {
    const int kr = ((c >> 1) * 16) + (l & 15);
    const int d0 = ((c & 1) * 32) + (l >> 4) * 8;
    *(bf16x8*)(kfrag + dst) = *(const bf16x8*)&kt[kr][d0];
  }
  {
    bf16x8 f;
    const int col = c * 16 + (l & 15);
    const int r0 = (l >> 4) * 8;
#pragma unroll
    for (int j = 0; j < 8; ++j) f[j] = vt[r0 + j][col];
    *(bf16x8*)(vfrag + dst) = f;
  }
}

// ---- main flash-attention kernel ----
// grid = B*(S/16) = 1024 blocks (4/CU, 16 waves), 256 threads = 4 waves.
// Wave w, step s (32 steps) handles keys s*128 + w*32 of one 16-row q-tile.
// Latency plan (round-2 post-mortem: mask stream was thrashing L2, so K/V
// "L2 hits" were really L3/HBM misses with <400cy prefetch cover):
//   mask:  NON-TEMPORAL loads (zero reuse -> don't evict K/V from L2),
//          2 reg slots, distance 2 (~800cy)
//   K-frag: 2 reg slots, distance 2 (~800cy; L2-resident again with nt mask)
//   V-frag: 2 reg slots, distance 2, reloaded right after PV consumes
// QK^T swapped (A=K-frag, B=Q-frag) -> score layout S^T[key=quad*4+r][q=n16],
// mask loads contiguous dwordx4. No barriers in the loop. Epilogue: in-block
// merge + normalize + vectorized store.
__global__ __launch_bounds__(256, 4) void fa_kernel(
    const short* __restrict__ qb, const short* __restrict__ kfrag,
    const short* __restrict__ vfrag, const float* __restrict__ mask,
    float* __restrict__ out) {
  __shared__ __align__(16) short lds_p[4][16][40];
  __shared__ float lds_O[4][16][64];
  __shared__ float lds_l[4][16];

  const int tid = threadIdx.x;
  const int w = tid >> 6;
  const int lane = tid & 63;
  const int quad = lane >> 4;
  const int n16 = lane & 15;
  const int loff = lane * 8;

  // XCD-contiguous remap: each XCD's L2 keeps one batch-half's 1MB of K/V
  // frags resident while the (non-temporal) mask streams through.
  const int vb = ((blockIdx.x & 7) << 7) | (blockIdx.x >> 3);
  const int b = vb >> 8;
  const int q0 = (vb & 255) << 4;

  const short* qrow = qb + (size_t)(b * S_LEN + q0 + n16) * DH;
  const bf16x8 aQ0 = *(const bf16x8*)(qrow + quad * 8);
  const bf16x8 aQ1 = *(const bf16x8*)(qrow + 32 + quad * 8);

  f32x4 O0 = {0.f, 0.f, 0.f, 0.f}, O1 = O0, O2 = O0, O3 = O0;
  float lacc = 0.f;

  const float* mrow = mask + ((size_t)b * S_LEN + q0 + n16) * S_LEN + quad * 4;
  const short* kfb = kfrag + (size_t)(b * 128 + w) * 2048;
  const short* vfb = vfrag + (size_t)(b * 128 + w) * 2048;

  bf16x8 kA0, kA1, kA2, kA3, kB0, kB1, kB2, kB3;   // K: 2 slots, dist 2
  bf16x8 vA0, vA1, vA2, vA3, vB0, vB1, vB2, vB3;   // V: 2 slots, dist 2
  f32x4 mA0, mA1, mB0, mB1;                        // mask: 2 slots, dist 2

#define LOAD_BK(B0, B1, B2, B3, SS)                       \
  {                                                       \
    const short* kf_ = kfb + (size_t)(SS) * 8192 + loff;  \
    B0 = *(const bf16x8*)(kf_);                           \
    B1 = *(const bf16x8*)(kf_ + 512);                     \
    B2 = *(const bf16x8*)(kf_ + 1024);                    \
    B3 = *(const bf16x8*)(kf_ + 1536);                    \
  }

#define LOAD_BV(V0, V1, V2, V3, SS)                       \
  {                                                       \
    const short* vf_ = vfb + (size_t)(SS) * 8192 + loff;  \
    V0 = *(const bf16x8*)(vf_);                           \
    V1 = *(const bf16x8*)(vf_ + 512);                     \
    V2 = *(const bf16x8*)(vf_ + 1024);                    \
    V3 = *(const bf16x8*)(vf_ + 1536);                    \
  }

#define LOAD_MASK(D0, D1, LK)                                  \
  {                                                            \
    const float* mp_ = mrow + (LK);                            \
    D0 = __builtin_nontemporal_load((const f32x4*)mp_);        \
    D1 = __builtin_nontemporal_load((const f32x4*)(mp_ + 16)); \
  }

#define FA_STEP(K0, K1, K2, K3, V0, V1, V2, V3, M0, M1, SS)                \
  {                                                                        \
    const f32x4 z = {0.f, 0.f, 0.f, 0.f};                                  \
    f32x4 s0 = MFMA(K0, aQ0, z); s0 = MFMA(K1, aQ1, s0);                   \
    f32x4 s1 = MFMA(K2, aQ0, z); s1 = MFMA(K3, aQ1, s1);                   \
    LOAD_BK(K0, K1, K2, K3, ((SS) + 2) & 31); /* refill, dist 2 */         \
    float p0_[4], p1_[4];                                                  \
    _Pragma("unroll") for (int r = 0; r < 4; ++r) {                        \
      p0_[r] = __expf(s0[r] * 0.125f * M0[r]);                             \
      p1_[r] = __expf(s1[r] * 0.125f * M1[r]);                             \
      lacc += p0_[r] + p1_[r];                                             \
    }                                                                      \
    LOAD_MASK(M0, M1, (((SS) + 2) * 128 + w * 32) & 4095); /* dist 2 */    \
    bf16x4 w0_, w1_;                                                       \
    _Pragma("unroll") for (int r = 0; r < 4; ++r) {                        \
      w0_[r] = f2bf(p0_[r]); w1_[r] = f2bf(p1_[r]);                        \
    }                                                                      \
    *(bf16x4*)&lds_p[w][n16][quad * 4] = w0_;                              \
    *(bf16x4*)&lds_p[w][n16][16 + quad * 4] = w1_;                         \
    const bf16x8 aP = *(const bf16x8*)&lds_p[w][n16][quad * 8];            \
    O0 = MFMA(aP, V0, O0); O1 = MFMA(aP, V1, O1);                          \
    O2 = MFMA(aP, V2, O2); O3 = MFMA(aP, V3, O3);                          \
    LOAD_BV(V0, V1, V2, V3, ((SS) + 2) & 31); /* refill, dist 2 */         \
  }

  LOAD_BK(kA0, kA1, kA2, kA3, 0);
  LOAD_BK(kB0, kB1, kB2, kB3, 1);
  LOAD_BV(vA0, vA1, vA2, vA3, 0);
  LOAD_BV(vB0, vB1, vB2, vB3, 1);
  LOAD_MASK(mA0, mA1, w * 32);
  LOAD_MASK(mB0, mB1, 128 + w * 32);

#pragma unroll 1
  for (int it = 0; it < 16; ++it) {
    const int s2 = it * 2;
    FA_STEP(kA0, kA1, kA2, kA3, vA0, vA1, vA2, vA3, mA0, mA1, s2);
    FA_STEP(kB0, kB1, kB2, kB3, vB0, vB1, vB2, vB3, mB0, mB1, s2 + 1);
  }
#undef LOAD_BK
#undef LOAD_BV
#undef LOAD_MASK
#undef FA_STEP

  // wave-local row-sum: lane holds q=n16; fold the 4 quads (keys) together
  lacc += __shfl_xor(lacc, 16);
  lacc += __shfl_xor(lacc, 32);

  // dump per-wave partials; PV C/D layout: row(q) = quad*4+reg, col(d) = n16
#pragma unroll
  for (int r = 0; r < 4; ++r) {
    const int row = quad * 4 + r;
    lds_O[w][row][n16]      = O0[r];
    lds_O[w][row][16 + n16] = O1[r];
    lds_O[w][row][32 + n16] = O2[r];
    lds_O[w][row][48 + n16] = O3[r];
  }
  if (lane < 16) lds_l[w][lane] = lacc;
  __syncthreads();

  // merge 4 wave-partials, normalize, vectorized final store (no atomics)
  const int r = tid >> 4;
  const int c4 = (tid & 15) << 2;
  const float inv =
      1.0f / (lds_l[0][r] + lds_l[1][r] + lds_l[2][r] + lds_l[3][r]);
  f32x4 acc;
#pragma unroll
  for (int j = 0; j < 4; ++j)
    acc[j] = (lds_O[0][r][c4 + j] + lds_O[1][r][c4 + j] +
              lds_O[2][r][c4 + j] + lds_O[3][r][c4 + j]) * inv;
  *(f32x4*)(out + (size_t)(b * S_LEN + q0 + r) * DH + c4) = acc;
}

extern "C" void kernel_launch(void* const* d_in, const int* in_sizes, int n_in,
                              void* d_out, int out_size, void* d_ws, size_t ws_size,
                              hipStream_t stream) {
  const float* q = (const float*)d_in[0];
  const float* k = (const float*)d_in[1];
  const float* v = (const float*)d_in[2];
  const float* mask = (const float*)d_in[3];
  float* out = (float*)d_out;

  short* qb = (short*)d_ws;                                  // 2 MB
  short* kfrag = qb + (size_t)NBATCH * S_LEN * DH;           // 2 MB
  short* vfrag = kfrag + (size_t)NBATCH * S_LEN * DH;        // 2 MB

  cvt_q_kernel<<<(NBATCH * S_LEN * DH) / 1024, 256, 0, stream>>>(q, qb);
  cvt_frag_kernel<<<NBATCH * 128, 256, 0, stream>>>(k, v, kfrag, vfrag);
  fa_kernel<<<NBATCH * 256, 256, 0, stream>>>(qb, kfrag, vfrag, mask, out);
}

// Round 4
// 405.555 us; speedup vs baseline: 1.0340x; 1.0340x over previous
//
#include <hip/hip_runtime.h>
#include <hip/hip_bf16.h>

#define S_LEN 4096
#define DH 64
#define NBATCH 4

typedef __attribute__((ext_vector_type(8))) short bf16x8;   // 8 x bf16 (4 VGPRs)
typedef __attribute__((ext_vector_type(4))) short bf16x4;   // 4 x bf16
typedef __attribute__((ext_vector_type(4))) float f32x4;

static __device__ __forceinline__ short f2bf(float x) {
  __hip_bfloat16 h = __float2bfloat16(x);
  return *reinterpret_cast<short*>(&h);
}

#define MFMA(a, b, c) __builtin_amdgcn_mfma_f32_16x16x32_bf16((a), (b), (c), 0, 0, 0)

// ---- q fp32 -> bf16 ----
__global__ __launch_bounds__(256) void cvt_q_kernel(const float* __restrict__ q,
                                                    short* __restrict__ qb) {
  int i = (blockIdx.x * 256 + threadIdx.x) * 4;
  f32x4 x = *(const f32x4*)(q + i);
  bf16x4 o;
#pragma unroll
  for (int j = 0; j < 4; ++j) o[j] = f2bf(x[j]);
  *(bf16x4*)(qb + i) = o;
}

// ---- k,v fp32 -> pre-fragmented bf16 MFMA operand layout (unchanged) ----
__global__ __launch_bounds__(256) void cvt_frag_kernel(const float* __restrict__ k,
                                                       const float* __restrict__ v,
                                                       short* __restrict__ kfrag,
                                                       short* __restrict__ vfrag) {
  __shared__ short kt[32][80];
  __shared__ short vt[32][80];
  const int t = threadIdx.x;
  const int b = blockIdx.x >> 7;
  const int i = blockIdx.x & 127;
  const size_t src0 = ((size_t)b * S_LEN + i * 32) * DH;
  {
    const int row = t >> 3, c0 = (t & 7) * 8;
    const f32x4 xk0 = *(const f32x4*)(k + src0 + row * DH + c0);
    const f32x4 xk1 = *(const f32x4*)(k + src0 + row * DH + c0 + 4);
    const f32x4 xv0 = *(const f32x4*)(v + src0 + row * DH + c0);
    const f32x4 xv1 = *(const f32x4*)(v + src0 + row * DH + c0 + 4);
#pragma unroll
    for (int j = 0; j < 4; ++j) {
      kt[row][c0 + j] = f2bf(xk0[j]);  kt[row][c0 + 4 + j] = f2bf(xk1[j]);
      vt[row][c0 + j] = f2bf(xv0[j]);  vt[row][c0 + 4 + j] = f2bf(xv1[j]);
    }
  }
  __syncthreads();
  const int c = t >> 6, l = t & 63;
  const size_t dst = (((size_t)(b * 128 + i) * 4 + c) * 64 + l) * 8;
  {
    const int kr = ((c >> 1) * 16) + (l & 15);
    const int d0 = ((c & 1) * 32) + (l >> 4) * 8;
    *(bf16x8*)(kfrag + dst) = *(const bf16x8*)&kt[kr][d0];
  }
  {
    bf16x8 f;
    const int col = c * 16 + (l & 15);
    const int r0 = (l >> 4) * 8;
#pragma unroll
    for (int j = 0; j < 8; ++j) f[j] = vt[r0 + j][col];
    *(bf16x8*)(vfrag + dst) = f;
  }
}

// ---- main flash-attention kernel ----
// grid = B*(S/16) = 1024 blocks, 256 threads = 4 waves. Wave w, step s
// (32 steps) handles keys s*128 + w*32 of one 16-row q-tile.
// R4 theory: the per-step loads were being serialized by register-pressure-
// driven rescheduling (128-VGPR cap vs ~130-reg live set). Buy schedule slack:
// __launch_bounds__(256,3) -> ~170 VGPR cap, 3 blocks/CU (12 waves). Keep the
// full 2-slot double-buffer pipeline on K, V, AND mask (10 loads in flight,
// distance 2 ~= 800cy cover). Mask loads are PLAIN cached loads (R3's
// nontemporal hint lost the ~40% L3 hit rate on the 268MB stream: FETCH_SIZE
// was 158MB < 268MB in round 0).
// QK^T swapped (A=K-frag, B=Q-frag) -> score layout S^T[key=quad*4+r][q=n16],
// mask loads contiguous dwordx4. No barriers in the loop. Epilogue: in-block
// merge + normalize + vectorized store.
__global__ __launch_bounds__(256, 3) void fa_kernel(
    const short* __restrict__ qb, const short* __restrict__ kfrag,
    const short* __restrict__ vfrag, const float* __restrict__ mask,
    float* __restrict__ out) {
  __shared__ __align__(16) short lds_p[4][16][40];
  __shared__ float lds_O[4][16][64];
  __shared__ float lds_l[4][16];

  const int tid = threadIdx.x;
  const int w = tid >> 6;
  const int lane = tid & 63;
  const int quad = lane >> 4;
  const int n16 = lane & 15;
  const int loff = lane * 8;

  // XCD-contiguous remap: each XCD's L2 keeps one batch-half's 1MB of K/V
  // frags resident while the mask streams through.
  const int vb = ((blockIdx.x & 7) << 7) | (blockIdx.x >> 3);
  const int b = vb >> 8;
  const int q0 = (vb & 255) << 4;

  const short* qrow = qb + (size_t)(b * S_LEN + q0 + n16) * DH;
  const bf16x8 aQ0 = *(const bf16x8*)(qrow + quad * 8);
  const bf16x8 aQ1 = *(const bf16x8*)(qrow + 32 + quad * 8);

  f32x4 O0 = {0.f, 0.f, 0.f, 0.f}, O1 = O0, O2 = O0, O3 = O0;
  float lacc = 0.f;

  const float* mrow = mask + ((size_t)b * S_LEN + q0 + n16) * S_LEN + quad * 4;
  const short* kfb = kfrag + (size_t)(b * 128 + w) * 2048;
  const short* vfb = vfrag + (size_t)(b * 128 + w) * 2048;

  bf16x8 kA0, kA1, kA2, kA3, kB0, kB1, kB2, kB3;   // K: 2 slots, dist 2
  bf16x8 vA0, vA1, vA2, vA3, vB0, vB1, vB2, vB3;   // V: 2 slots, dist 2
  f32x4 mA0, mA1, mB0, mB1;                        // mask: 2 slots, dist 2

#define LOAD_BK(B0, B1, B2, B3, SS)                       \
  {                                                       \
    const short* kf_ = kfb + (size_t)(SS) * 8192 + loff;  \
    B0 = *(const bf16x8*)(kf_);                           \
    B1 = *(const bf16x8*)(kf_ + 512);                     \
    B2 = *(const bf16x8*)(kf_ + 1024);                    \
    B3 = *(const bf16x8*)(kf_ + 1536);                    \
  }

#define LOAD_BV(V0, V1, V2, V3, SS)                       \
  {                                                       \
    const short* vf_ = vfb + (size_t)(SS) * 8192 + loff;  \
    V0 = *(const bf16x8*)(vf_);                           \
    V1 = *(const bf16x8*)(vf_ + 512);                     \
    V2 = *(const bf16x8*)(vf_ + 1024);                    \
    V3 = *(const bf16x8*)(vf_ + 1536);                    \
  }

#define LOAD_MASK(D0, D1, LK)                             \
  {                                                       \
    const float* mp_ = mrow + (LK);                       \
    D0 = *(const f32x4*)(mp_);                            \
    D1 = *(const f32x4*)(mp_ + 16);                       \
  }

#define FA_STEP(K0, K1, K2, K3, V0, V1, V2, V3, M0, M1, SS)                \
  {                                                                        \
    const f32x4 z = {0.f, 0.f, 0.f, 0.f};                                  \
    f32x4 s0 = MFMA(K0, aQ0, z); s0 = MFMA(K1, aQ1, s0);                   \
    f32x4 s1 = MFMA(K2, aQ0, z); s1 = MFMA(K3, aQ1, s1);                   \
    LOAD_BK(K0, K1, K2, K3, ((SS) + 2) & 31); /* refill, dist 2 */         \
    float p0_[4], p1_[4];                                                  \
    _Pragma("unroll") for (int r = 0; r < 4; ++r) {                        \
      p0_[r] = __expf(s0[r] * 0.125f * M0[r]);                             \
      p1_[r] = __expf(s1[r] * 0.125f * M1[r]);                             \
      lacc += p0_[r] + p1_[r];                                             \
    }                                                                      \
    LOAD_MASK(M0, M1, (((SS) + 2) * 128 + w * 32) & 4095); /* dist 2 */    \
    bf16x4 w0_, w1_;                                                       \
    _Pragma("unroll") for (int r = 0; r < 4; ++r) {                        \
      w0_[r] = f2bf(p0_[r]); w1_[r] = f2bf(p1_[r]);                        \
    }                                                                      \
    *(bf16x4*)&lds_p[w][n16][quad * 4] = w0_;                              \
    *(bf16x4*)&lds_p[w][n16][16 + quad * 4] = w1_;                         \
    const bf16x8 aP = *(const bf16x8*)&lds_p[w][n16][quad * 8];            \
    O0 = MFMA(aP, V0, O0); O1 = MFMA(aP, V1, O1);                          \
    O2 = MFMA(aP, V2, O2); O3 = MFMA(aP, V3, O3);                          \
    LOAD_BV(V0, V1, V2, V3, ((SS) + 2) & 31); /* refill, dist 2 */         \
  }

  LOAD_BK(kA0, kA1, kA2, kA3, 0);
  LOAD_BK(kB0, kB1, kB2, kB3, 1);
  LOAD_BV(vA0, vA1, vA2, vA3, 0);
  LOAD_BV(vB0, vB1, vB2, vB3, 1);
  LOAD_MASK(mA0, mA1, w * 32);
  LOAD_MASK(mB0, mB1, 128 + w * 32);

#pragma unroll 1
  for (int it = 0; it < 16; ++it) {
    const int s2 = it * 2;
    FA_STEP(kA0, kA1, kA2, kA3, vA0, vA1, vA2, vA3, mA0, mA1, s2);
    FA_STEP(kB0, kB1, kB2, kB3, vB0, vB1, vB2, vB3, mB0, mB1, s2 + 1);
  }
#undef LOAD_BK
#undef LOAD_BV
#undef LOAD_MASK
#undef FA_STEP

  // wave-local row-sum: lane holds q=n16; fold the 4 quads (keys) together
  lacc += __shfl_xor(lacc, 16);
  lacc += __shfl_xor(lacc, 32);

  // dump per-wave partials; PV C/D layout: row(q) = quad*4+reg, col(d) = n16
#pragma unroll
  for (int r = 0; r < 4; ++r) {
    const int row = quad * 4 + r;
    lds_O[w][row][n16]      = O0[r];
    lds_O[w][row][16 + n16] = O1[r];
    lds_O[w][row][32 + n16] = O2[r];
    lds_O[w][row][48 + n16] = O3[r];
  }
  if (lane < 16) lds_l[w][lane] = lacc;
  __syncthreads();

  // merge 4 wave-partials, normalize, vectorized final store (no atomics)
  const int r = tid >> 4;
  const int c4 = (tid & 15) << 2;
  const float inv =
      1.0f / (lds_l[0][r] + lds_l[1][r] + lds_l[2][r] + lds_l[3][r]);
  f32x4 acc;
#pragma unroll
  for (int j = 0; j < 4; ++j)
    acc[j] = (lds_O[0][r][c4 + j] + lds_O[1][r][c4 + j] +
              lds_O[2][r][c4 + j] + lds_O[3][r][c4 + j]) * inv;
  *(f32x4*)(out + (size_t)(b * S_LEN + q0 + r) * DH + c4) = acc;
}

extern "C" void kernel_launch(void* const* d_in, const int* in_sizes, int n_in,
                              void* d_out, int out_size, void* d_ws, size_t ws_size,
                              hipStream_t stream) {
  const float* q = (const float*)d_in[0];
  const float* k = (const float*)d_in[1];
  const float* v = (const float*)d_in[2];
  const float* mask = (const float*)d_in[3];
  float* out = (float*)d_out;

  short* qb = (short*)d_ws;                                  // 2 MB
  short* kfrag = qb + (size_t)NBATCH * S_LEN * DH;           // 2 MB
  short* vfrag = kfrag + (size_t)NBATCH * S_LEN * DH;        // 2 MB

  cvt_q_kernel<<<(NBATCH * S_LEN * DH) / 1024, 256, 0, stream>>>(q, qb);
  cvt_frag_kernel<<<NBATCH * 128, 256, 0, stream>>>(k, v, kfrag, vfrag);
  fa_kernel<<<NBATCH * 256, 256, 0, stream>>>(qb, kfrag, vfrag, mask, out);
}

// Round 5
// 402.922 us; speedup vs baseline: 1.0407x; 1.0065x over previous
//
#include <hip/hip_runtime.h>
#include <hip/hip_bf16.h>

#define S_LEN 4096
#define DH 64
#define NBATCH 4

typedef __attribute__((ext_vector_type(8))) short bf16x8;   // 8 x bf16 (4 VGPRs)
typedef __attribute__((ext_vector_type(4))) short bf16x4;   // 4 x bf16
typedef __attribute__((ext_vector_type(4))) float f32x4;

static __device__ __forceinline__ short f2bf(float x) {
  __hip_bfloat16 h = __float2bfloat16(x);
  return *reinterpret_cast<short*>(&h);
}

#define MFMA(a, b, c) __builtin_amdgcn_mfma_f32_16x16x32_bf16((a), (b), (c), 0, 0, 0)

// ---- q fp32 -> bf16 ----
__global__ __launch_bounds__(256) void cvt_q_kernel(const float* __restrict__ q,
                                                    short* __restrict__ qb) {
  int i = (blockIdx.x * 256 + threadIdx.x) * 4;
  f32x4 x = *(const f32x4*)(q + i);
  bf16x4 o;
#pragma unroll
  for (int j = 0; j < 4; ++j) o[j] = f2bf(x[j]);
  *(bf16x4*)(qb + i) = o;
}

// ---- k,v fp32 -> pre-fragmented bf16 MFMA operand layout (unchanged) ----
__global__ __launch_bounds__(256) void cvt_frag_kernel(const float* __restrict__ k,
                                                       const float* __restrict__ v,
                                                       short* __restrict__ kfrag,
                                                       short* __restrict__ vfrag) {
  __shared__ short kt[32][80];
  __shared__ short vt[32][80];
  const int t = threadIdx.x;
  const int b = blockIdx.x >> 7;
  const int i = blockIdx.x & 127;
  const size_t src0 = ((size_t)b * S_LEN + i * 32) * DH;
  {
    const int row = t >> 3, c0 = (t & 7) * 8;
    const f32x4 xk0 = *(const f32x4*)(k + src0 + row * DH + c0);
    const f32x4 xk1 = *(const f32x4*)(k + src0 + row * DH + c0 + 4);
    const f32x4 xv0 = *(const f32x4*)(v + src0 + row * DH + c0);
    const f32x4 xv1 = *(const f32x4*)(v + src0 + row * DH + c0 + 4);
#pragma unroll
    for (int j = 0; j < 4; ++j) {
      kt[row][c0 + j] = f2bf(xk0[j]);  kt[row][c0 + 4 + j] = f2bf(xk1[j]);
      vt[row][c0 + j] = f2bf(xv0[j]);  vt[row][c0 + 4 + j] = f2bf(xv1[j]);
    }
  }
  __syncthreads();
  const int c = t >> 6, l = t & 63;
  const size_t dst = (((size_t)(b * 128 + i) * 4 + c) * 64 + l) * 8;
  {
    const int kr = ((c >> 1) * 16) + (l & 15);
    const int d0 = ((c & 1) * 32) + (l >> 4) * 8;
    *(bf16x8*)(kfrag + dst) = *(const bf16x8*)&kt[kr][d0];
  }
  {
    bf16x8 f;
    const int col = c * 16 + (l & 15);
    const int r0 = (l >> 4) * 8;
#pragma unroll
    for (int j = 0; j < 8; ++j) f[j] = vt[r0 + j][col];
    *(bf16x8*)(vfrag + dst) = f;
  }
}

// ---- main flash-attention kernel ----
// R5 theory: fa was CACHE-BANDWIDTH bound, not latency bound (R2-R4 latency
// knobs all null; 1.34 GB of L2/L3 traffic / 135us = ~10 TB/s = plausible
// ceiling). Traffic was 1.07 GB K/V re-reads + 268 MB compulsory mask.
// Fix: 4x q-reuse. grid = 256 blocks (1/CU), 512 threads = 8 waves
// (4 q-groups x 2-way key split). Block owns 64 q-rows x all 4096 keys.
// The 4 waves sharing a key-split index load IDENTICAL K/V fragment addresses
// each step -> 3 of 4 hits in L1; L2-side K/V traffic drops to 268 MB.
// Per-wave inner loop is unchanged (16 q x 32 keys/step, now 64 steps).
// __launch_bounds__(512,2) -> 256-VGPR cap: the ~180-reg pipeline (K 2-slot,
// V 2-slot, mask 4-slot dist-4) finally has allocator slack.
__global__ __launch_bounds__(512, 2) void fa_kernel(
    const short* __restrict__ qb, const short* __restrict__ kfrag,
    const short* __restrict__ vfrag, const float* __restrict__ mask,
    float* __restrict__ out) {
  __shared__ __align__(16) short lds_p[8][16][40];
  __shared__ float lds_O[8][16][64];
  __shared__ float lds_l[8][16];

  const int tid = threadIdx.x;
  const int w = tid >> 6;          // 0..7
  const int wq = w >> 1;           // q-group 0..3 (16 rows each)
  const int wk = w & 1;            // key-split 0..1
  const int lane = tid & 63;
  const int quad = lane >> 4;
  const int n16 = lane & 15;
  const int loff = lane * 8;

  // XCD remap: 256 blocks = 8 XCDs x 32; two XCDs per batch keep that batch's
  // 4MB of K/V frags L2-resident while the mask streams through.
  const int vb = ((blockIdx.x & 7) << 5) | (blockIdx.x >> 3);
  const int b = vb >> 6;
  const int q0 = (vb & 63) << 6;   // 64 q-rows per block

  const int qr = q0 + wq * 16 + n16;          // this lane's q row
  const short* qrow = qb + (size_t)(b * S_LEN + qr) * DH;
  const bf16x8 aQ0 = *(const bf16x8*)(qrow + quad * 8);
  const bf16x8 aQ1 = *(const bf16x8*)(qrow + 32 + quad * 8);

  f32x4 O0 = {0.f, 0.f, 0.f, 0.f}, O1 = O0, O2 = O0, O3 = O0;
  float lacc = 0.f;

  const float* mrow = mask + ((size_t)b * S_LEN + qr) * S_LEN + quad * 4;
  const short* kfb = kfrag + (size_t)(b * 128 + wk) * 2048;
  const short* vfb = vfrag + (size_t)(b * 128 + wk) * 2048;

  bf16x8 kA0, kA1, kA2, kA3, kB0, kB1, kB2, kB3;   // K: 2 slots, dist 2
  bf16x8 vA0, vA1, vA2, vA3, vB0, vB1, vB2, vB3;   // V: 2 slots, dist 2
  f32x4 mA0, mA1, mB0, mB1, mC0, mC1, mD0, mD1;    // mask: 4 slots, dist 4

#define LOAD_BK(B0, B1, B2, B3, SS)                       \
  {                                                       \
    const short* kf_ = kfb + (size_t)(SS) * 4096 + loff;  \
    B0 = *(const bf16x8*)(kf_);                           \
    B1 = *(const bf16x8*)(kf_ + 512);                     \
    B2 = *(const bf16x8*)(kf_ + 1024);                    \
    B3 = *(const bf16x8*)(kf_ + 1536);                    \
  }

#define LOAD_BV(V0, V1, V2, V3, SS)                       \
  {                                                       \
    const short* vf_ = vfb + (size_t)(SS) * 4096 + loff;  \
    V0 = *(const bf16x8*)(vf_);                           \
    V1 = *(const bf16x8*)(vf_ + 512);                     \
    V2 = *(const bf16x8*)(vf_ + 1024);                    \
    V3 = *(const bf16x8*)(vf_ + 1536);                    \
  }

#define LOAD_MASK(D0, D1, LK)                             \
  {                                                       \
    const float* mp_ = mrow + (LK);                       \
    D0 = *(const f32x4*)(mp_);                            \
    D1 = *(const f32x4*)(mp_ + 16);                       \
  }

#define FA_STEP(K0, K1, K2, K3, V0, V1, V2, V3, M0, M1, SS)                \
  {                                                                        \
    const f32x4 z = {0.f, 0.f, 0.f, 0.f};                                  \
    f32x4 s0 = MFMA(K0, aQ0, z); s0 = MFMA(K1, aQ1, s0);                   \
    f32x4 s1 = MFMA(K2, aQ0, z); s1 = MFMA(K3, aQ1, s1);                   \
    LOAD_BK(K0, K1, K2, K3, ((SS) + 2) & 63); /* refill, dist 2 */         \
    float p0_[4], p1_[4];                                                  \
    _Pragma("unroll") for (int r = 0; r < 4; ++r) {                        \
      p0_[r] = __expf(s0[r] * 0.125f * M0[r]);                             \
      p1_[r] = __expf(s1[r] * 0.125f * M1[r]);                             \
      lacc += p0_[r] + p1_[r];                                             \
    }                                                                      \
    LOAD_MASK(M0, M1, (((SS) + 4) * 64 + wk * 32) & 4095); /* dist 4 */    \
    bf16x4 w0_, w1_;                                                       \
    _Pragma("unroll") for (int r = 0; r < 4; ++r) {                        \
      w0_[r] = f2bf(p0_[r]); w1_[r] = f2bf(p1_[r]);                        \
    }                                                                      \
    *(bf16x4*)&lds_p[w][n16][quad * 4] = w0_;                              \
    *(bf16x4*)&lds_p[w][n16][16 + quad * 4] = w1_;                         \
    const bf16x8 aP = *(const bf16x8*)&lds_p[w][n16][quad * 8];            \
    O0 = MFMA(aP, V0, O0); O1 = MFMA(aP, V1, O1);                          \
    O2 = MFMA(aP, V2, O2); O3 = MFMA(aP, V3, O3);                          \
    LOAD_BV(V0, V1, V2, V3, ((SS) + 2) & 63); /* refill, dist 2 */         \
  }

  LOAD_BK(kA0, kA1, kA2, kA3, 0);
  LOAD_BK(kB0, kB1, kB2, kB3, 1);
  LOAD_BV(vA0, vA1, vA2, vA3, 0);
  LOAD_BV(vB0, vB1, vB2, vB3, 1);
  LOAD_MASK(mA0, mA1, wk * 32);
  LOAD_MASK(mB0, mB1, 64 + wk * 32);
  LOAD_MASK(mC0, mC1, 128 + wk * 32);
  LOAD_MASK(mD0, mD1, 192 + wk * 32);

#pragma unroll 1
  for (int it = 0; it < 16; ++it) {
    const int s4 = it * 4;
    FA_STEP(kA0, kA1, kA2, kA3, vA0, vA1, vA2, vA3, mA0, mA1, s4);
    FA_STEP(kB0, kB1, kB2, kB3, vB0, vB1, vB2, vB3, mB0, mB1, s4 + 1);
    FA_STEP(kA0, kA1, kA2, kA3, vA0, vA1, vA2, vA3, mC0, mC1, s4 + 2);
    FA_STEP(kB0, kB1, kB2, kB3, vB0, vB1, vB2, vB3, mD0, mD1, s4 + 3);
  }
#undef LOAD_BK
#undef LOAD_BV
#undef LOAD_MASK
#undef FA_STEP

  // wave-local row-sum: lane holds q=n16; fold the 4 quads (keys) together
  lacc += __shfl_xor(lacc, 16);
  lacc += __shfl_xor(lacc, 32);

  // dump per-wave partials; PV C/D layout: row(q) = quad*4+reg, col(d) = n16
#pragma unroll
  for (int r = 0; r < 4; ++r) {
    const int row = quad * 4 + r;
    lds_O[w][row][n16]      = O0[r];
    lds_O[w][row][16 + n16] = O1[r];
    lds_O[w][row][32 + n16] = O2[r];
    lds_O[w][row][48 + n16] = O3[r];
  }
  if (lane < 16) lds_l[w][lane] = lacc;
  __syncthreads();

  // merge the 2 key-split partials per q-group, normalize, vectorized store.
  // 512 threads: g = q-group (128 thr each), r = row, c8 = 8-col chunk.
  const int g = tid >> 7;
  const int r = (tid >> 3) & 15;
  const int c8 = (tid & 7) << 3;
  const int w0 = g * 2, w1 = g * 2 + 1;
  const float inv = 1.0f / (lds_l[w0][r] + lds_l[w1][r]);
  float* op = out + (size_t)(b * S_LEN + q0 + g * 16 + r) * DH + c8;
  f32x4 acc0, acc1;
#pragma unroll
  for (int j = 0; j < 4; ++j) {
    acc0[j] = (lds_O[w0][r][c8 + j]     + lds_O[w1][r][c8 + j])     * inv;
    acc1[j] = (lds_O[w0][r][c8 + 4 + j] + lds_O[w1][r][c8 + 4 + j]) * inv;
  }
  *(f32x4*)(op) = acc0;
  *(f32x4*)(op + 4) = acc1;
}

extern "C" void kernel_launch(void* const* d_in, const int* in_sizes, int n_in,
                              void* d_out, int out_size, void* d_ws, size_t ws_size,
                              hipStream_t stream) {
  const float* q = (const float*)d_in[0];
  const float* k = (const float*)d_in[1];
  const float* v = (const float*)d_in[2];
  const float* mask = (const float*)d_in[3];
  float* out = (float*)d_out;

  short* qb = (short*)d_ws;                                  // 2 MB
  short* kfrag = qb + (size_t)NBATCH * S_LEN * DH;           // 2 MB
  short* vfrag = kfrag + (size_t)NBATCH * S_LEN * DH;        // 2 MB

  cvt_q_kernel<<<(NBATCH * S_LEN * DH) / 1024, 256, 0, stream>>>(q, qb);
  cvt_frag_kernel<<<NBATCH * 128, 256, 0, stream>>>(k, v, kfrag, vfrag);
  fa_kernel<<<NBATCH * 64, 512, 0, stream>>>(qb, kfrag, vfrag, mask, out);
}

// Round 6
// 393.425 us; speedup vs baseline: 1.0659x; 1.0241x over previous
//
#include <hip/hip_runtime.h>
#include <hip/hip_bf16.h>

#define S_LEN 4096
#define DH 64
#define NBATCH 4

typedef __attribute__((ext_vector_type(8))) short bf16x8;   // 8 x bf16 (4 VGPRs)
typedef __attribute__((ext_vector_type(4))) short bf16x4;   // 4 x bf16
typedef __attribute__((ext_vector_type(4))) float f32x4;

static __device__ __forceinline__ short f2bf(float x) {
  __hip_bfloat16 h = __float2bfloat16(x);
  return *reinterpret_cast<short*>(&h);
}

#define MFMA(a, b, c) __builtin_amdgcn_mfma_f32_16x16x32_bf16((a), (b), (c), 0, 0, 0)

// ---- q fp32 -> bf16 ----
__global__ __launch_bounds__(256) void cvt_q_kernel(const float* __restrict__ q,
                                                    short* __restrict__ qb) {
  int i = (blockIdx.x * 256 + threadIdx.x) * 4;
  f32x4 x = *(const f32x4*)(q + i);
  bf16x4 o;
#pragma unroll
  for (int j = 0; j < 4; ++j) o[j] = f2bf(x[j]);
  *(bf16x4*)(qb + i) = o;
}

// ---- k,v fp32 -> pre-fragmented bf16 MFMA operand layout (unchanged) ----
__global__ __launch_bounds__(256) void cvt_frag_kernel(const float* __restrict__ k,
                                                       const float* __restrict__ v,
                                                       short* __restrict__ kfrag,
                                                       short* __restrict__ vfrag) {
  __shared__ short kt[32][80];
  __shared__ short vt[32][80];
  const int t = threadIdx.x;
  const int b = blockIdx.x >> 7;
  const int i = blockIdx.x & 127;
  const size_t src0 = ((size_t)b * S_LEN + i * 32) * DH;
  {
    const int row = t >> 3, c0 = (t & 7) * 8;
    const f32x4 xk0 = *(const f32x4*)(k + src0 + row * DH + c0);
    const f32x4 xk1 = *(const f32x4*)(k + src0 + row * DH + c0 + 4);
    const f32x4 xv0 = *(const f32x4*)(v + src0 + row * DH + c0);
    const f32x4 xv1 = *(const f32x4*)(v + src0 + row * DH + c0 + 4);
#pragma unroll
    for (int j = 0; j < 4; ++j) {
      kt[row][c0 + j] = f2bf(xk0[j]);  kt[row][c0 + 4 + j] = f2bf(xk1[j]);
      vt[row][c0 + j] = f2bf(xv0[j]);  vt[row][c0 + 4 + j] = f2bf(xv1[j]);
    }
  }
  __syncthreads();
  const int c = t >> 6, l = t & 63;
  const size_t dst = (((size_t)(b * 128 + i) * 4 + c) * 64 + l) * 8;
  {
    const int kr = ((c >> 1) * 16) + (l & 15);
    const int d0 = ((c & 1) * 32) + (l >> 4) * 8;
    *(bf16x8*)(kfrag + dst) = *(const bf16x8*)&kt[kr][d0];
  }
  {
    bf16x8 f;
    const int col = c * 16 + (l & 15);
    const int r0 = (l >> 4) * 8;
#pragma unroll
    for (int j = 0; j < 8; ++j) f[j] = vt[r0 + j][col];
    *(bf16x8*)(vfrag + dst) = f;
  }
}

// ---- main flash-attention kernel ----
// R6 theory: fa was TA/segment-bound (~96 VMEM segments per wave-step; L1 hits
// still traverse TA, so R5's L1-sharing was null). Fix: block-cooperative LDS
// staging de-duplicates K/V and coalesces the mask.
// grid = 256 blocks (1/CU), 512 thr = 8 waves = 4 q-groups x 2 key-splits.
// Block: 64 q-rows x 4096 keys, 64 block-steps of 64 keys. Per step each wave
// issues FOUR global loads (1KB K-frag, 1KB V-frag, 2x coalesced 4-row mask
// f32x4) -> ~32 segments/wave-step (was ~96). Depth-1 double buffer: issue
// loads for s+1, compute s from LDS, ds_write stage, one barrier (T14: HBM
// latency hides under compute). Mask tile XOR-swizzled per row (g ^= r&7) on
// BOTH write and read -> 2-way banks (free) instead of 16-way.
// Math core (swapped QK^T, P LDS round-trip, epilogue) byte-identical to R5.
__global__ __launch_bounds__(512, 2) void fa_kernel(
    const short* __restrict__ qb, const short* __restrict__ kfrag,
    const short* __restrict__ vfrag, const float* __restrict__ mask,
    float* __restrict__ out) {
  __shared__ __align__(16) short kst[2][2][4][512];   // 16 KB: K stage
  __shared__ __align__(16) short vst[2][2][4][512];   // 16 KB: V stage
  __shared__ __align__(16) float mst[2][4096];        // 32 KB: mask stage (swz)
  __shared__ __align__(16) short lds_p[8][16][40];
  __shared__ float lds_O[8][16][64];
  __shared__ float lds_l[8][16];

  const int tid = threadIdx.x;
  const int w = tid >> 6;          // 0..7
  const int wq = w >> 1;           // q-group 0..3 (16 rows each)
  const int wk = w & 1;            // key-split 0..1
  const int lane = tid & 63;
  const int quad = lane >> 4;
  const int n16 = lane & 15;
  const int loff = lane * 8;

  // XCD remap: 256 blocks = 8 XCDs x 32 -> per-XCD L2 keeps one batch-half's
  // K/V frags resident while the mask streams through.
  const int vb = ((blockIdx.x & 7) << 5) | (blockIdx.x >> 3);
  const int b = vb >> 6;
  const int q0 = (vb & 63) << 6;   // 64 q-rows per block

  const int qr = q0 + wq * 16 + n16;          // this lane's q row
  const short* qrow = qb + (size_t)(b * S_LEN + qr) * DH;
  const bf16x8 aQ0 = *(const bf16x8*)(qrow + quad * 8);
  const bf16x8 aQ1 = *(const bf16x8*)(qrow + 32 + quad * 8);

  f32x4 O0 = {0.f, 0.f, 0.f, 0.f}, O1 = O0, O2 = O0, O3 = O0;
  float lacc = 0.f;

  // ---- staging assignments (per wave / per lane, loop-invariant) ----
  // K/V: wave w stages split ksp=w>>2, frag kfr=w&3 (1KB contiguous each).
  const int ksp = w >> 2, kfr = w & 3;
  const short* kbase =
      kfrag + (size_t)(b * 128 + ksp) * 2048 + kfr * 512 + loff;
  const short* vbase =
      vfrag + (size_t)(b * 128 + ksp) * 2048 + kfr * 512 + loff;
  // mask: wave w stages rows w*8..w*8+7 (two 4-row instrs), granule sg=16B.
  const int srow0 = w * 8 + (lane >> 4);      // rows for h=0 instr
  const int srow1 = srow0 + 4;                // rows for h=1 instr
  const int sg = lane & 15;
  const float* msrc0 =
      mask + ((size_t)b * S_LEN + q0 + srow0) * S_LEN + sg * 4;
  const float* msrc1 =
      mask + ((size_t)b * S_LEN + q0 + srow1) * S_LEN + sg * 4;
  const int wslot0 = srow0 * 64 + (sg ^ (srow0 & 7)) * 4;   // swizzled write
  const int wslot1 = srow1 * 64 + (sg ^ (srow1 & 7)) * 4;
  // mask read slots for this lane's (q-row, key cols), swizzle-matched:
  const int mr = wq * 16 + n16;
  const int rslot0 = mr * 64 + (((wk * 8 + quad) ^ (mr & 7)) * 4);
  const int rslot1 = mr * 64 + (((wk * 8 + 4 + quad) ^ (mr & 7)) * 4);

#define STEP(CUR, SS)                                                      \
  {                                                                        \
    const int sn_ = ((SS) + 1) & 63; /* prefetch step (wraps harmlessly) */\
    const bf16x8 kR = *(const bf16x8*)(kbase + (size_t)sn_ * 4096);        \
    const bf16x8 vR = *(const bf16x8*)(vbase + (size_t)sn_ * 4096);        \
    const f32x4 mR0 = *(const f32x4*)(msrc0 + sn_ * 64);                   \
    const f32x4 mR1 = *(const f32x4*)(msrc1 + sn_ * 64);                   \
    const f32x4 z = {0.f, 0.f, 0.f, 0.f};                                  \
    f32x4 s0 = MFMA(*(const bf16x8*)&kst[CUR][wk][0][loff], aQ0, z);       \
    s0 = MFMA(*(const bf16x8*)&kst[CUR][wk][1][loff], aQ1, s0);            \
    f32x4 s1 = MFMA(*(const bf16x8*)&kst[CUR][wk][2][loff], aQ0, z);       \
    s1 = MFMA(*(const bf16x8*)&kst[CUR][wk][3][loff], aQ1, s1);            \
    const f32x4 M0 = *(const f32x4*)&mst[CUR][rslot0];                     \
    const f32x4 M1 = *(const f32x4*)&mst[CUR][rslot1];                     \
    float p0_[4], p1_[4];                                                  \
    _Pragma("unroll") for (int r = 0; r < 4; ++r) {                        \
      p0_[r] = __expf(s0[r] * 0.125f * M0[r]);                             \
      p1_[r] = __expf(s1[r] * 0.125f * M1[r]);                             \
      lacc += p0_[r] + p1_[r];                                             \
    }                                                                      \
    bf16x4 w0_, w1_;                                                       \
    _Pragma("unroll") for (int r = 0; r < 4; ++r) {                        \
      w0_[r] = f2bf(p0_[r]); w1_[r] = f2bf(p1_[r]);                        \
    }                                                                      \
    *(bf16x4*)&lds_p[w][n16][quad * 4] = w0_;                              \
    *(bf16x4*)&lds_p[w][n16][16 + quad * 4] = w1_;                         \
    const bf16x8 aP = *(const bf16x8*)&lds_p[w][n16][quad * 8];            \
    O0 = MFMA(aP, *(const bf16x8*)&vst[CUR][wk][0][loff], O0);             \
    O1 = MFMA(aP, *(const bf16x8*)&vst[CUR][wk][1][loff], O1);             \
    O2 = MFMA(aP, *(const bf16x8*)&vst[CUR][wk][2][loff], O2);             \
    O3 = MFMA(aP, *(const bf16x8*)&vst[CUR][wk][3][loff], O3);             \
    *(bf16x8*)&kst[(CUR) ^ 1][ksp][kfr][loff] = kR;                        \
    *(bf16x8*)&vst[(CUR) ^ 1][ksp][kfr][loff] = vR;                        \
    *(f32x4*)&mst[(CUR) ^ 1][wslot0] = mR0;                                \
    *(f32x4*)&mst[(CUR) ^ 1][wslot1] = mR1;                                \
    __syncthreads();                                                       \
  }

  // prologue: stage step 0 into buffer 0
  {
    const bf16x8 kR = *(const bf16x8*)(kbase);
    const bf16x8 vR = *(const bf16x8*)(vbase);
    const f32x4 mR0 = *(const f32x4*)(msrc0);
    const f32x4 mR1 = *(const f32x4*)(msrc1);
    *(bf16x8*)&kst[0][ksp][kfr][loff] = kR;
    *(bf16x8*)&vst[0][ksp][kfr][loff] = vR;
    *(f32x4*)&mst[0][wslot0] = mR0;
    *(f32x4*)&mst[0][wslot1] = mR1;
    __syncthreads();
  }

#pragma unroll 1
  for (int it = 0; it < 32; ++it) {
    STEP(0, 2 * it);
    STEP(1, 2 * it + 1);
  }
#undef STEP

  // wave-local row-sum: lane holds q=n16; fold the 4 quads (keys) together
  lacc += __shfl_xor(lacc, 16);
  lacc += __shfl_xor(lacc, 32);

  // dump per-wave partials; PV C/D layout: row(q) = quad*4+reg, col(d) = n16
#pragma unroll
  for (int r = 0; r < 4; ++r) {
    const int row = quad * 4 + r;
    lds_O[w][row][n16]      = O0[r];
    lds_O[w][row][16 + n16] = O1[r];
    lds_O[w][row][32 + n16] = O2[r];
    lds_O[w][row][48 + n16] = O3[r];
  }
  if (lane < 16) lds_l[w][lane] = lacc;
  __syncthreads();

  // merge the 2 key-split partials per q-group, normalize, vectorized store.
  const int g = tid >> 7;
  const int r = (tid >> 3) & 15;
  const int c8 = (tid & 7) << 3;
  const int w0 = g * 2, w1 = g * 2 + 1;
  const float inv = 1.0f / (lds_l[w0][r] + lds_l[w1][r]);
  float* op = out + (size_t)(b * S_LEN + q0 + g * 16 + r) * DH + c8;
  f32x4 acc0, acc1;
#pragma unroll
  for (int j = 0; j < 4; ++j) {
    acc0[j] = (lds_O[w0][r][c8 + j]     + lds_O[w1][r][c8 + j])     * inv;
    acc1[j] = (lds_O[w0][r][c8 + 4 + j] + lds_O[w1][r][c8 + 4 + j]) * inv;
  }
  *(f32x4*)(op) = acc0;
  *(f32x4*)(op + 4) = acc1;
}

extern "C" void kernel_launch(void* const* d_in, const int* in_sizes, int n_in,
                              void* d_out, int out_size, void* d_ws, size_t ws_size,
                              hipStream_t stream) {
  const float* q = (const float*)d_in[0];
  const float* k = (const float*)d_in[1];
  const float* v = (const float*)d_in[2];
  const float* mask = (const float*)d_in[3];
  float* out = (float*)d_out;

  short* qb = (short*)d_ws;                                  // 2 MB
  short* kfrag = qb + (size_t)NBATCH * S_LEN * DH;           // 2 MB
  short* vfrag = kfrag + (size_t)NBATCH * S_LEN * DH;        // 2 MB

  cvt_q_kernel<<<(NBATCH * S_LEN * DH) / 1024, 256, 0, stream>>>(q, qb);
  cvt_frag_kernel<<<NBATCH * 128, 256, 0, stream>>>(k, v, kfrag, vfrag);
  fa_kernel<<<NBATCH * 64, 512, 0, stream>>>(qb, kfrag, vfrag, mask, out);
}

// Round 7
// 390.059 us; speedup vs baseline: 1.0751x; 1.0086x over previous
//
#include <hip/hip_runtime.h>
#include <hip/hip_bf16.h>

#define S_LEN 4096
#define DH 64
#define NBATCH 4

typedef __attribute__((ext_vector_type(8))) short bf16x8;   // 8 x bf16 (4 VGPRs)
typedef __attribute__((ext_vector_type(4))) short bf16x4;   // 4 x bf16
typedef __attribute__((ext_vector_type(4))) float f32x4;

static __device__ __forceinline__ short f2bf(float x) {
  __hip_bfloat16 h = __float2bfloat16(x);
  return *reinterpret_cast<short*>(&h);
}

// async global->LDS DMA, 16B per lane. LDS dest = wave-uniform base + lane*16;
// global src is per-lane. Counts against vmcnt only.
static __device__ __forceinline__ void gl_lds16(const void* g, void* l) {
  __builtin_amdgcn_global_load_lds(
      (const __attribute__((address_space(1))) void*)g,
      (__attribute__((address_space(3))) void*)l, 16, 0, 0);
}

#define MFMA(a, b, c) __builtin_amdgcn_mfma_f32_16x16x32_bf16((a), (b), (c), 0, 0, 0)

// ---- q fp32 -> bf16 ----
__global__ __launch_bounds__(256) void cvt_q_kernel(const float* __restrict__ q,
                                                    short* __restrict__ qb) {
  int i = (blockIdx.x * 256 + threadIdx.x) * 4;
  f32x4 x = *(const f32x4*)(q + i);
  bf16x4 o;
#pragma unroll
  for (int j = 0; j < 4; ++j) o[j] = f2bf(x[j]);
  *(bf16x4*)(qb + i) = o;
}

// ---- k,v fp32 -> pre-fragmented bf16 MFMA operand layout (unchanged) ----
__global__ __launch_bounds__(256) void cvt_frag_kernel(const float* __restrict__ k,
                                                       const float* __restrict__ v,
                                                       short* __restrict__ kfrag,
                                                       short* __restrict__ vfrag) {
  __shared__ short kt[32][80];
  __shared__ short vt[32][80];
  const int t = threadIdx.x;
  const int b = blockIdx.x >> 7;
  const int i = blockIdx.x & 127;
  const size_t src0 = ((size_t)b * S_LEN + i * 32) * DH;
  {
    const int row = t >> 3, c0 = (t & 7) * 8;
    const f32x4 xk0 = *(const f32x4*)(k + src0 + row * DH + c0);
    const f32x4 xk1 = *(const f32x4*)(k + src0 + row * DH + c0 + 4);
    const f32x4 xv0 = *(const f32x4*)(v + src0 + row * DH + c0);
    const f32x4 xv1 = *(const f32x4*)(v + src0 + row * DH + c0 + 4);
#pragma unroll
    for (int j = 0; j < 4; ++j) {
      kt[row][c0 + j] = f2bf(xk0[j]);  kt[row][c0 + 4 + j] = f2bf(xk1[j]);
      vt[row][c0 + j] = f2bf(xv0[j]);  vt[row][c0 + 4 + j] = f2bf(xv1[j]);
    }
  }
  __syncthreads();
  const int c = t >> 6, l = t & 63;
  const size_t dst = (((size_t)(b * 128 + i) * 4 + c) * 64 + l) * 8;
  {
    const int kr = ((c >> 1) * 16) + (l & 15);
    const int d0 = ((c & 1) * 32) + (l >> 4) * 8;
    *(bf16x8*)(kfrag + dst) = *(const bf16x8*)&kt[kr][d0];
  }
  {
    bf16x8 f;
    const int col = c * 16 + (l & 15);
    const int r0 = (l >> 4) * 8;
#pragma unroll
    for (int j = 0; j < 8; ++j) f[j] = vt[r0 + j][col];
    *(bf16x8*)(vfrag + dst) = f;
  }
}

// ---- main flash-attention kernel ----
// R7: T3+T4 counted-vmcnt async pipeline (the one technique not yet tried; all
// prior variants drained the memory pipe at a sync wait each step).
// grid = 256 blocks (1/CU), 512 thr = 8 waves = 4 q-groups x 2 key-splits.
// 64 block-steps of 64 keys. Staging = global_load_lds DMA into 3 rotating
// 32KB LDS step-buffers ([K 8K][V 8K][mask 16K], lane-linear). Each wave
// issues exactly 4 DMA loads/step, 2 steps ahead -> 8 in flight, waited with
// inline-asm s_waitcnt vmcnt(4)+s_barrier (NEVER 0 in-loop): loads stay in
// flight across barriers; pipe never drains.
// Mask swizzle moved to the GLOBAL SOURCE (pre-swizzled granule: lane fetches
// granule (l&15)^(row&7)) so LDS dest stays linear; read slots identical to
// R6's proven formulas -> math bit-identical (absmax must stay 0.0009765625).
// Epilogue LDS (O-partials) aliases the stage area after a vmcnt(0) drain.
__global__ __launch_bounds__(512, 2) void fa_kernel(
    const short* __restrict__ qb, const short* __restrict__ kfrag,
    const short* __restrict__ vfrag, const float* __restrict__ mask,
    float* __restrict__ out) {
  __shared__ __align__(16) char sstage[3 * 32768];   // 96 KB: 3 step buffers
  __shared__ __align__(16) short lds_p[8][16][40];   // 10 KB: P round-trip

  const int tid = threadIdx.x;
  const int w = tid >> 6;          // 0..7
  const int wq = w >> 1;           // q-group 0..3 (16 rows each)
  const int wk = w & 1;            // key-split 0..1
  const int lane = tid & 63;
  const int quad = lane >> 4;
  const int n16 = lane & 15;
  const int loff = lane * 8;       // shorts

  // XCD remap: 256 blocks = 8 XCDs x 32 -> per-XCD L2 keeps one batch-half's
  // K/V frags resident while the mask streams through.
  const int vb = ((blockIdx.x & 7) << 5) | (blockIdx.x >> 3);
  const int b = vb >> 6;
  const int q0 = (vb & 63) << 6;   // 64 q-rows per block

  const int qr = q0 + wq * 16 + n16;
  const short* qrow = qb + (size_t)(b * S_LEN + qr) * DH;
  const bf16x8 aQ0 = *(const bf16x8*)(qrow + quad * 8);
  const bf16x8 aQ1 = *(const bf16x8*)(qrow + 32 + quad * 8);

  f32x4 O0 = {0.f, 0.f, 0.f, 0.f}, O1 = O0, O2 = O0, O3 = O0;
  float lacc = 0.f;

  // ---- staging sources (per-lane) ----
  // K/V: wave w stages split ksp=w>>2, frag kfr=w&3 (1KB contiguous each).
  const int ksp = w >> 2, kfr = w & 3;
  const short* kbase =
      kfrag + (size_t)(b * 128 + ksp) * 2048 + kfr * 512 + loff;
  const short* vbase =
      vfrag + (size_t)(b * 128 + ksp) * 2048 + kfr * 512 + loff;
  // mask: wave w stages rows w*8..w*8+7 via two DMA instrs (4 rows each);
  // source granule pre-swizzled: lane fetches granule (l&15)^(row&7).
  const int srow0 = w * 8 + (lane >> 4);
  const int srow1 = srow0 + 4;
  const int sg = lane & 15;
  const float* msrc0 =
      mask + ((size_t)b * S_LEN + q0 + srow0) * S_LEN + (sg ^ (srow0 & 7)) * 4;
  const float* msrc1 =
      mask + ((size_t)b * S_LEN + q0 + srow1) * S_LEN + (sg ^ (srow1 & 7)) * 4;

  // wave-uniform LDS staging offsets (bytes within a step buffer)
  const int kdst = ksp * 4096 + kfr * 1024;
  const int vdst = 8192 + kdst;
  const int mdst0 = 16384 + w * 2048;
  const int mdst1 = mdst0 + 1024;

  // mask read slots (floats within the 16KB mask region) — same as R6
  const int mr = wq * 16 + n16;
  const int rslot0 = mr * 64 + ((wk * 8 + quad) ^ (mr & 7)) * 4;
  const int rslot1 = mr * 64 + ((wk * 8 + 4 + quad) ^ (mr & 7)) * 4;

  // retire Q's vmem so in-loop vmcnt counting sees staging DMAs only
  asm volatile("s_waitcnt vmcnt(0)" ::: "memory");

#define STAGE(SB, SS)                                        \
  {                                                          \
    const int sn_ = (SS) & 63;                               \
    gl_lds16(kbase + (size_t)sn_ * 4096, (SB) + kdst);       \
    gl_lds16(vbase + (size_t)sn_ * 4096, (SB) + vdst);       \
    gl_lds16(msrc0 + (size_t)sn_ * 64, (SB) + mdst0);        \
    gl_lds16(msrc1 + (size_t)sn_ * 64, (SB) + mdst1);        \
  }

#define COMPUTE(SB)                                                        \
  {                                                                        \
    const short* kk_ = (const short*)((SB) + wk * 4096) + loff;            \
    const short* vv_ = (const short*)((SB) + 8192 + wk * 4096) + loff;     \
    const float* mm_ = (const float*)((SB) + 16384);                       \
    const f32x4 z = {0.f, 0.f, 0.f, 0.f};                                  \
    f32x4 s0 = MFMA(*(const bf16x8*)(kk_), aQ0, z);                        \
    s0 = MFMA(*(const bf16x8*)(kk_ + 512), aQ1, s0);                       \
    f32x4 s1 = MFMA(*(const bf16x8*)(kk_ + 1024), aQ0, z);                 \
    s1 = MFMA(*(const bf16x8*)(kk_ + 1536), aQ1, s1);                      \
    const f32x4 M0 = *(const f32x4*)(mm_ + rslot0);                        \
    const f32x4 M1 = *(const f32x4*)(mm_ + rslot1);                        \
    float p0_[4], p1_[4];                                                  \
    _Pragma("unroll") for (int r = 0; r < 4; ++r) {                        \
      p0_[r] = __expf(s0[r] * 0.125f * M0[r]);                             \
      p1_[r] = __expf(s1[r] * 0.125f * M1[r]);                             \
      lacc += p0_[r] + p1_[r];                                             \
    }                                                                      \
    bf16x4 w0_, w1_;                                                       \
    _Pragma("unroll") for (int r = 0; r < 4; ++r) {                        \
      w0_[r] = f2bf(p0_[r]); w1_[r] = f2bf(p1_[r]);                        \
    }                                                                      \
    *(bf16x4*)&lds_p[w][n16][quad * 4] = w0_;                              \
    *(bf16x4*)&lds_p[w][n16][16 + quad * 4] = w1_;                         \
    const bf16x8 aP = *(const bf16x8*)&lds_p[w][n16][quad * 8];            \
    O0 = MFMA(aP, *(const bf16x8*)(vv_), O0);                              \
    O1 = MFMA(aP, *(const bf16x8*)(vv_ + 512), O1);                        \
    O2 = MFMA(aP, *(const bf16x8*)(vv_ + 1024), O2);                       \
    O3 = MFMA(aP, *(const bf16x8*)(vv_ + 1536), O3);                       \
  }

  char* bufA = sstage;            // compute from this (step s)
  char* bufB = sstage + 32768;    // step s+1 in flight
  char* bufC = sstage + 65536;    // stage target (step s+2)
  STAGE(bufA, 0);
  STAGE(bufB, 1);

#pragma unroll 1
  for (int s = 0; s < 64; ++s) {
    // wait my 4 oldest DMAs (step s) — 8 newer stay in flight; then sync so
    // ALL waves' step-s data is in LDS. Never vmcnt(0) in-loop (T4).
    asm volatile("s_waitcnt vmcnt(4)\n\ts_barrier" ::: "memory");
    STAGE(bufC, s + 2);   // overwrites step s-1's buffer: safe post-barrier
    COMPUTE(bufA);
    char* t_ = bufA; bufA = bufB; bufB = bufC; bufC = t_;
  }
#undef STAGE
#undef COMPUTE

  // drain all DMAs before aliasing the stage area for the epilogue
  asm volatile("s_waitcnt vmcnt(0)\n\ts_barrier" ::: "memory");

  float* ldsO = (float*)sstage;            // [8][16][64]
  float* ldsl = (float*)(sstage + 32768);  // [8][16]

  // wave-local row-sum: lane holds q=n16; fold the 4 quads (keys) together
  lacc += __shfl_xor(lacc, 16);
  lacc += __shfl_xor(lacc, 32);

  // dump per-wave partials; PV C/D layout: row(q) = quad*4+reg, col(d) = n16
#pragma unroll
  for (int r = 0; r < 4; ++r) {
    const int row = quad * 4 + r;
    float* od = ldsO + (w * 16 + row) * 64;
    od[n16]      = O0[r];
    od[16 + n16] = O1[r];
    od[32 + n16] = O2[r];
    od[48 + n16] = O3[r];
  }
  if (lane < 16) ldsl[w * 16 + lane] = lacc;
  __syncthreads();

  // merge the 2 key-split partials per q-group, normalize, vectorized store.
  const int g = tid >> 7;
  const int rr = (tid >> 3) & 15;
  const int c8 = (tid & 7) << 3;
  const int wa = g * 2, wb = g * 2 + 1;
  const float inv = 1.0f / (ldsl[wa * 16 + rr] + ldsl[wb * 16 + rr]);
  const float* oap = ldsO + (wa * 16 + rr) * 64 + c8;
  const float* obp = ldsO + (wb * 16 + rr) * 64 + c8;
  float* op = out + (size_t)(b * S_LEN + q0 + g * 16 + rr) * DH + c8;
  f32x4 acc0, acc1;
#pragma unroll
  for (int j = 0; j < 4; ++j) {
    acc0[j] = (oap[j]     + obp[j])     * inv;
    acc1[j] = (oap[4 + j] + obp[4 + j]) * inv;
  }
  *(f32x4*)(op) = acc0;
  *(f32x4*)(op + 4) = acc1;
}

extern "C" void kernel_launch(void* const* d_in, const int* in_sizes, int n_in,
                              void* d_out, int out_size, void* d_ws, size_t ws_size,
                              hipStream_t stream) {
  const float* q = (const float*)d_in[0];
  const float* k = (const float*)d_in[1];
  const float* v = (const float*)d_in[2];
  const float* mask = (const float*)d_in[3];
  float* out = (float*)d_out;

  short* qb = (short*)d_ws;                                  // 2 MB
  short* kfrag = qb + (size_t)NBATCH * S_LEN * DH;           // 2 MB
  short* vfrag = kfrag + (size_t)NBATCH * S_LEN * DH;        // 2 MB

  cvt_q_kernel<<<(NBATCH * S_LEN * DH) / 1024, 256, 0, stream>>>(q, qb);
  cvt_frag_kernel<<<NBATCH * 128, 256, 0, stream>>>(k, v, kfrag, vfrag);
  fa_kernel<<<NBATCH * 64, 512, 0, stream>>>(qb, kfrag, vfrag, mask, out);
}

// Round 8
// 388.645 us; speedup vs baseline: 1.0790x; 1.0036x over previous
//
#include <hip/hip_runtime.h>
#include <hip/hip_bf16.h>

#define S_LEN 4096
#define DH 64
#define NBATCH 4

typedef __attribute__((ext_vector_type(8))) short bf16x8;   // 8 x bf16 (4 VGPRs)
typedef __attribute__((ext_vector_type(4))) short bf16x4;   // 4 x bf16
typedef __attribute__((ext_vector_type(4))) float f32x4;

static __device__ __forceinline__ short f2bf(float x) {
  __hip_bfloat16 h = __float2bfloat16(x);
  return *reinterpret_cast<short*>(&h);
}

// async global->LDS DMA, 16B/lane: LDS dest = wave-uniform base + lane*16,
// global src per-lane. Counts against vmcnt only.
static __device__ __forceinline__ void gl_lds16(const void* g, void* l) {
  __builtin_amdgcn_global_load_lds(
      (const __attribute__((address_space(1))) void*)g,
      (__attribute__((address_space(3))) void*)l, 16, 0, 0);
}

#define MFMA(a, b, c) __builtin_amdgcn_mfma_f32_16x16x32_bf16((a), (b), (c), 0, 0, 0)

// ---- q fp32 -> bf16 ----
__global__ __launch_bounds__(256) void cvt_q_kernel(const float* __restrict__ q,
                                                    short* __restrict__ qb) {
  int i = (blockIdx.x * 256 + threadIdx.x) * 4;
  f32x4 x = *(const f32x4*)(q + i);
  bf16x4 o;
#pragma unroll
  for (int j = 0; j < 4; ++j) o[j] = f2bf(x[j]);
  *(bf16x4*)(qb + i) = o;
}

// ---- k,v fp32 -> pre-fragmented bf16 MFMA operand layout (unchanged) ----
__global__ __launch_bounds__(256) void cvt_frag_kernel(const float* __restrict__ k,
                                                       const float* __restrict__ v,
                                                       short* __restrict__ kfrag,
                                                       short* __restrict__ vfrag) {
  __shared__ short kt[32][80];
  __shared__ short vt[32][80];
  const int t = threadIdx.x;
  const int b = blockIdx.x >> 7;
  const int i = blockIdx.x & 127;
  const size_t src0 = ((size_t)b * S_LEN + i * 32) * DH;
  {
    const int row = t >> 3, c0 = (t & 7) * 8;
    const f32x4 xk0 = *(const f32x4*)(k + src0 + row * DH + c0);
    const f32x4 xk1 = *(const f32x4*)(k + src0 + row * DH + c0 + 4);
    const f32x4 xv0 = *(const f32x4*)(v + src0 + row * DH + c0);
    const f32x4 xv1 = *(const f32x4*)(v + src0 + row * DH + c0 + 4);
#pragma unroll
    for (int j = 0; j < 4; ++j) {
      kt[row][c0 + j] = f2bf(xk0[j]);  kt[row][c0 + 4 + j] = f2bf(xk1[j]);
      vt[row][c0 + j] = f2bf(xv0[j]);  vt[row][c0 + 4 + j] = f2bf(xv1[j]);
    }
  }
  __syncthreads();
  const int c = t >> 6, l = t & 63;
  const size_t dst = (((size_t)(b * 128 + i) * 4 + c) * 64 + l) * 8;
  {
    const int kr = ((c >> 1) * 16) + (l & 15);
    const int d0 = ((c & 1) * 32) + (l >> 4) * 8;
    *(bf16x8*)(kfrag + dst) = *(const bf16x8*)&kt[kr][d0];
  }
  {
    bf16x8 f;
    const int col = c * 16 + (l & 15);
    const int r0 = (l >> 4) * 8;
#pragma unroll
    for (int j = 0; j < 8; ++j) f[j] = vt[r0 + j][col];
    *(bf16x8*)(vfrag + dst) = f;
  }
}

// ---- main flash-attention kernel ----
// R8 theory: the invariant across all prior variants was DRAM burst length —
// every structure touched each 16KB mask row in 128-256B strips across ~16K
// concurrent row-streams, destroying HBM page locality (~2 TB/s effective;
// explains why occupancy/prefetch/traffic/scheduling knobs were ALL null).
// Fix: stage mask in SUPER-STEPS of 256 keys; each of the wave's 8 DMA instrs
// covers ONE ROW x 1KB CONTIGUOUS (64 lanes x 16B) -> 4-8x longer bursts.
// Shell unchanged from R6/R7: 256 blocks (1/CU), 512 thr = 8 waves =
// 4 q-groups x 2 key-splits, 64-q block, identical math core (bit-identical
// output). K/V = R5's register 2-slot double-buffer from L2. Mask LDS
// double-buffered 2x64KB; one vmcnt(16)+barrier per super-step retires the 8
// mask DMAs + older K/V while keeping the 16 newest K/V prefetches in flight.
// Swizzle: read granule XOR row&7 (2-way banks); DMA SOURCE pre-swizzled with
// the same involution (lane fetches granule lane^j) so LDS dest stays linear.
__global__ __launch_bounds__(512, 2) void fa_kernel(
    const short* __restrict__ qb, const short* __restrict__ kfrag,
    const short* __restrict__ vfrag, const float* __restrict__ mask,
    float* __restrict__ out) {
  __shared__ __align__(16) float mst[2][16384];      // 2 x 64KB mask stage
  __shared__ __align__(16) short lds_p[8][16][40];   // P round-trip

  const int tid = threadIdx.x;
  const int w = tid >> 6;          // 0..7
  const int wq = w >> 1;           // q-group 0..3 (16 rows each)
  const int wk = w & 1;            // key-split 0..1
  const int lane = tid & 63;
  const int quad = lane >> 4;
  const int n16 = lane & 15;
  const int loff = lane * 8;       // shorts

  // XCD remap: per-XCD L2 keeps one batch-half's K/V frags resident.
  const int vb = ((blockIdx.x & 7) << 5) | (blockIdx.x >> 3);
  const int b = vb >> 6;
  const int q0 = (vb & 63) << 6;   // 64 q-rows per block

  const int qr = q0 + wq * 16 + n16;
  const short* qrow = qb + (size_t)(b * S_LEN + qr) * DH;
  const bf16x8 aQ0 = *(const bf16x8*)(qrow + quad * 8);
  const bf16x8 aQ1 = *(const bf16x8*)(qrow + 32 + quad * 8);

  f32x4 O0 = {0.f, 0.f, 0.f, 0.f}, O1 = O0, O2 = O0, O3 = O0;
  float lacc = 0.f;

  // K/V register staging (R5 formulas, proven)
  const short* kfb = kfrag + (size_t)(b * 128 + wk) * 2048;
  const short* vfb = vfrag + (size_t)(b * 128 + wk) * 2048;
  bf16x8 kA0, kA1, kA2, kA3, kB0, kB1, kB2, kB3;
  bf16x8 vA0, vA1, vA2, vA3, vB0, vB1, vB2, vB3;

  // mask staging: wave w stages rows w*8+j (j=0..7), 1KB contiguous per row
  // per super-step; source granule = lane ^ j (pre-swizzle involution).
  const float* mbase =
      mask + ((size_t)b * S_LEN + q0 + w * 8) * S_LEN;   // row w*8, col 0
  // mask read slots (floats within 64KB buffer), granule ^= row&7 = n16&7:
  const int mr = wq * 16 + n16;
  const int mx = n16 & 7;
  int rs0[4], rs1[4];
#pragma unroll
  for (int ssl = 0; ssl < 4; ++ssl) {
    rs0[ssl] = mr * 256 + (((ssl * 16) + wk * 8 + quad) ^ mx) * 4;
    rs1[ssl] = mr * 256 + (((ssl * 16) + wk * 8 + 4 + quad) ^ mx) * 4;
  }

#define STAGE(BUF, SS)                                                     \
  {                                                                        \
    const int c0_ = (SS) * 256;                                            \
    _Pragma("unroll") for (int j = 0; j < 8; ++j) {                        \
      gl_lds16(mbase + (size_t)j * S_LEN + c0_ + ((lane ^ j) << 2),        \
               (char*)&mst[BUF][0] + (w * 8 + j) * 1024);                  \
    }                                                                      \
  }

#define LOAD_BK(B0, B1, B2, B3, SS)                       \
  {                                                       \
    const short* kf_ = kfb + (size_t)(SS) * 4096 + loff;  \
    B0 = *(const bf16x8*)(kf_);                           \
    B1 = *(const bf16x8*)(kf_ + 512);                     \
    B2 = *(const bf16x8*)(kf_ + 1024);                    \
    B3 = *(const bf16x8*)(kf_ + 1536);                    \
  }

#define LOAD_BV(V0, V1, V2, V3, SS)                       \
  {                                                       \
    const short* vf_ = vfb + (size_t)(SS) * 4096 + loff;  \
    V0 = *(const bf16x8*)(vf_);                           \
    V1 = *(const bf16x8*)(vf_ + 512);                     \
    V2 = *(const bf16x8*)(vf_ + 1024);                    \
    V3 = *(const bf16x8*)(vf_ + 1536);                    \
  }

#define SUB(K0, K1, K2, K3, V0, V1, V2, V3, MB, SSL, GS)                   \
  {                                                                        \
    const f32x4 z = {0.f, 0.f, 0.f, 0.f};                                  \
    f32x4 s0 = MFMA(K0, aQ0, z); s0 = MFMA(K1, aQ1, s0);                   \
    f32x4 s1 = MFMA(K2, aQ0, z); s1 = MFMA(K3, aQ1, s1);                   \
    LOAD_BK(K0, K1, K2, K3, ((GS) + 2) & 63); /* refill, dist 2 */         \
    const f32x4 M0 = *(const f32x4*)((MB) + rs0[SSL]);                     \
    const f32x4 M1 = *(const f32x4*)((MB) + rs1[SSL]);                     \
    float p0_[4], p1_[4];                                                  \
    _Pragma("unroll") for (int r = 0; r < 4; ++r) {                        \
      p0_[r] = __expf(s0[r] * 0.125f * M0[r]);                             \
      p1_[r] = __expf(s1[r] * 0.125f * M1[r]);                             \
      lacc += p0_[r] + p1_[r];                                             \
    }                                                                      \
    bf16x4 w0_, w1_;                                                       \
    _Pragma("unroll") for (int r = 0; r < 4; ++r) {                        \
      w0_[r] = f2bf(p0_[r]); w1_[r] = f2bf(p1_[r]);                        \
    }                                                                      \
    *(bf16x4*)&lds_p[w][n16][quad * 4] = w0_;                              \
    *(bf16x4*)&lds_p[w][n16][16 + quad * 4] = w1_;                         \
    const bf16x8 aP = *(const bf16x8*)&lds_p[w][n16][quad * 8];            \
    O0 = MFMA(aP, V0, O0); O1 = MFMA(aP, V1, O1);                          \
    O2 = MFMA(aP, V2, O2); O3 = MFMA(aP, V3, O3);                          \
    LOAD_BV(V0, V1, V2, V3, ((GS) + 2) & 63); /* refill, dist 2 */         \
  }

  // prologue: stage super-step 0 (8 DMA), prefetch K/V sub-steps 0,1 (16);
  // vmcnt(16) retires exactly the 8 mask DMAs.
  STAGE(0, 0);
  LOAD_BK(kA0, kA1, kA2, kA3, 0);
  LOAD_BV(vA0, vA1, vA2, vA3, 0);
  LOAD_BK(kB0, kB1, kB2, kB3, 1);
  LOAD_BV(vB0, vB1, vB2, vB3, 1);
  asm volatile("s_waitcnt vmcnt(16)\n\ts_barrier" ::: "memory");

  int buf = 0;
#pragma unroll 1
  for (int s = 0; s < 16; ++s) {
    STAGE(buf ^ 1, (s + 1) & 15);   // 8 DMA for next super-step
    const float* mb = &mst[buf][0];
    const int gs = s * 4;
    SUB(kA0, kA1, kA2, kA3, vA0, vA1, vA2, vA3, mb, 0, gs);
    SUB(kB0, kB1, kB2, kB3, vB0, vB1, vB2, vB3, mb, 1, gs + 1);
    SUB(kA0, kA1, kA2, kA3, vA0, vA1, vA2, vA3, mb, 2, gs + 2);
    SUB(kB0, kB1, kB2, kB3, vB0, vB1, vB2, vB3, mb, 3, gs + 3);
    // retire the 8 mask DMAs (+ older K/V); keep newest 16 K/V in flight.
    asm volatile("s_waitcnt vmcnt(16)\n\ts_barrier" ::: "memory");
    buf ^= 1;
  }
#undef STAGE
#undef LOAD_BK
#undef LOAD_BV
#undef SUB

  // drain all DMAs before aliasing the stage area for the epilogue
  asm volatile("s_waitcnt vmcnt(0)\n\ts_barrier" ::: "memory");

  float* ldsO = &mst[0][0];   // [8][16][64] = 32 KB
  float* ldsl = &mst[1][0];   // [8][16]

  // wave-local row-sum: lane holds q=n16; fold the 4 quads (keys) together
  lacc += __shfl_xor(lacc, 16);
  lacc += __shfl_xor(lacc, 32);

  // dump per-wave partials; PV C/D layout: row(q) = quad*4+reg, col(d) = n16
#pragma unroll
  for (int r = 0; r < 4; ++r) {
    const int row = quad * 4 + r;
    float* od = ldsO + (w * 16 + row) * 64;
    od[n16]      = O0[r];
    od[16 + n16] = O1[r];
    od[32 + n16] = O2[r];
    od[48 + n16] = O3[r];
  }
  if (lane < 16) ldsl[w * 16 + lane] = lacc;
  __syncthreads();

  // merge the 2 key-split partials per q-group, normalize, vectorized store.
  const int g = tid >> 7;
  const int rr = (tid >> 3) & 15;
  const int c8 = (tid & 7) << 3;
  const int wa = g * 2, wb = g * 2 + 1;
  const float inv = 1.0f / (ldsl[wa * 16 + rr] + ldsl[wb * 16 + rr]);
  const float* oap = ldsO + (wa * 16 + rr) * 64 + c8;
  const float* obp = ldsO + (wb * 16 + rr) * 64 + c8;
  float* op = out + (size_t)(b * S_LEN + q0 + g * 16 + rr) * DH + c8;
  f32x4 acc0, acc1;
#pragma unroll
  for (int j = 0; j < 4; ++j) {
    acc0[j] = (oap[j]     + obp[j])     * inv;
    acc1[j] = (oap[4 + j] + obp[4 + j]) * inv;
  }
  *(f32x4*)(op) = acc0;
  *(f32x4*)(op + 4) = acc1;
}

extern "C" void kernel_launch(void* const* d_in, const int* in_sizes, int n_in,
                              void* d_out, int out_size, void* d_ws, size_t ws_size,
                              hipStream_t stream) {
  const float* q = (const float*)d_in[0];
  const float* k = (const float*)d_in[1];
  const float* v = (const float*)d_in[2];
  const float* mask = (const float*)d_in[3];
  float* out = (float*)d_out;

  short* qb = (short*)d_ws;                                  // 2 MB
  short* kfrag = qb + (size_t)NBATCH * S_LEN * DH;           // 2 MB
  short* vfrag = kfrag + (size_t)NBATCH * S_LEN * DH;        // 2 MB

  cvt_q_kernel<<<(NBATCH * S_LEN * DH) / 1024, 256, 0, stream>>>(q, qb);
  cvt_frag_kernel<<<NBATCH * 128, 256, 0, stream>>>(k, v, kfrag, vfrag);
  fa_kernel<<<NBATCH * 64, 512, 0, stream>>>(qb, kfrag, vfrag, mask, out);
}